// Round 2
// baseline (117.945 us; speedup 1.0000x reference)
//
#include <hip/hip_runtime.h>
#include <hip/hip_bf16.h>

#define NPTS 384
#define DIMS 256
#define TI 4      // i-rows per block in main kernel
#define JC 48     // j-columns per block in main kernel

// ---------------------------------------------------------------------------
// Kernel A: row squared-norms for both matrices + zero the output scalar.
// grid (96, 2): blockIdx.y selects matrix; block = 256 threads = 4 waves;
// wave w reduces row blockIdx.x*4 + w (256 floats = 1 float4 per lane).
// ---------------------------------------------------------------------------
__global__ __launch_bounds__(256) void prep_kernel(
        const float* __restrict__ Es, const float* __restrict__ Et,
        float* __restrict__ sqn /* [2][NPTS] */, float* __restrict__ out) {
    const float* __restrict__ E = (blockIdx.y == 0) ? Es : Et;
    const int wave = threadIdx.x >> 6;
    const int lane = threadIdx.x & 63;
    const int row  = blockIdx.x * 4 + wave;

    const float4 v = ((const float4*)(E + row * DIMS))[lane];
    float s = v.x * v.x + v.y * v.y + v.z * v.z + v.w * v.w;
#pragma unroll
    for (int off = 32; off > 0; off >>= 1)
        s += __shfl_down(s, off, 64);
    if (lane == 0) sqn[blockIdx.y * NPTS + row] = s;
    if (blockIdx.x == 0 && blockIdx.y == 0 && threadIdx.x == 0) out[0] = 0.0f;
}

// ---------------------------------------------------------------------------
// Kernel B: Gram tile (32x32 per block, 2x2 micro-tile) WITHOUT LDS —
// E is L1/L2-resident, float4 loads. Fused epilogue writes:
//   G[i][j]  = e_i . e_j
//   RC[i][j] = { R, C } = { (i==j ? 0 : 1/max(||e_i-e_j||,eps)),  G_ii - G_ij }
// grid (12, 12, 2): z selects matrix.
// ---------------------------------------------------------------------------
__global__ __launch_bounds__(256) void gram_kernel(
        const float* __restrict__ Es, const float* __restrict__ Et,
        const float* __restrict__ sqn,
        float* __restrict__ Gs, float* __restrict__ Gt,
        float2* __restrict__ RCs, float2* __restrict__ RCt) {
    const int z = blockIdx.z;
    const float* __restrict__ E  = z ? Et : Es;
    float*       __restrict__ G  = z ? Gt : Gs;
    float2*      __restrict__ RC = z ? RCt : RCs;
    const float* __restrict__ sq = sqn + z * NPTS;

    const int tx = threadIdx.x;   // 0..15
    const int ty = threadIdx.y;   // 0..15
    const int i  = blockIdx.x * 32 + 2 * ty;
    const int j  = blockIdx.y * 32 + 2 * tx;

    const float4* __restrict__ a0 = (const float4*)(E + i * DIMS);
    const float4* __restrict__ a1 = (const float4*)(E + (i + 1) * DIMS);
    const float4* __restrict__ b0 = (const float4*)(E + j * DIMS);
    const float4* __restrict__ b1 = (const float4*)(E + (j + 1) * DIMS);

    float g00 = 0.f, g01 = 0.f, g10 = 0.f, g11 = 0.f;
#pragma unroll 8
    for (int k = 0; k < DIMS / 4; k++) {
        float4 av0 = a0[k], av1 = a1[k], bv0 = b0[k], bv1 = b1[k];
        g00 = fmaf(av0.x, bv0.x, g00); g00 = fmaf(av0.y, bv0.y, g00);
        g00 = fmaf(av0.z, bv0.z, g00); g00 = fmaf(av0.w, bv0.w, g00);
        g01 = fmaf(av0.x, bv1.x, g01); g01 = fmaf(av0.y, bv1.y, g01);
        g01 = fmaf(av0.z, bv1.z, g01); g01 = fmaf(av0.w, bv1.w, g01);
        g10 = fmaf(av1.x, bv0.x, g10); g10 = fmaf(av1.y, bv0.y, g10);
        g10 = fmaf(av1.z, bv0.z, g10); g10 = fmaf(av1.w, bv0.w, g10);
        g11 = fmaf(av1.x, bv1.x, g11); g11 = fmaf(av1.y, bv1.y, g11);
        g11 = fmaf(av1.z, bv1.z, g11); g11 = fmaf(av1.w, bv1.w, g11);
    }

    const float sii0 = sq[i], sii1 = sq[i + 1];
    const float sjj0 = sq[j], sjj1 = sq[j + 1];

    float g[2][2] = {{g00, g01}, {g10, g11}};
    float si[2] = {sii0, sii1};
    float sj[2] = {sjj0, sjj1};
#pragma unroll
    for (int r = 0; r < 2; r++) {
#pragma unroll
        for (int c = 0; c < 2; c++) {
            int ii = i + r, jj = j + c;
            float gv = g[r][c];
            float v  = si[r] + sj[c] - 2.0f * gv;
            float n  = sqrtf(fmaxf(v, 0.0f));
            float rr = (ii == jj) ? 0.0f : (1.0f / fmaxf(n, 1e-12f));
            G[ii * NPTS + jj]  = gv;
            RC[ii * NPTS + jj] = make_float2(rr, si[r] - gv);
        }
    }
}

// ---------------------------------------------------------------------------
// Kernel C: main triple reduction. Block: TI i-rows x JC j-cols, 384 threads
// (thread == k). All (i,j)-dependent values are wave-uniform -> s_load from
// global (RC packed float2). Per-thread k-dependent values in VGPRs.
//   angle = R_ij * fma(R_ik, G_jk + C_ij, -R_ik*G_ik)
//   smooth_l1(d) = 0.5 * med3(d*d, 2|d|-1, 1)
// ---------------------------------------------------------------------------
__global__ __launch_bounds__(NPTS) void rkd_main_kernel(
        const float* __restrict__ Gs, const float* __restrict__ Gt,
        const float2* __restrict__ RCs, const float2* __restrict__ RCt,
        float* __restrict__ out) {
    const int k  = threadIdx.x;            // 0..383
    const int i0 = blockIdx.x * TI;
    const int j0 = blockIdx.y * JC;

    // per-thread (k-dependent) setup: R_ik and -R_ik*G_ik for each i-row
    float ru_s[TI], vu_s[TI], ru_t[TI], vu_t[TI];
#pragma unroll
    for (int r = 0; r < TI; r++) {
        const int row = (i0 + r) * NPTS + k;
        float rs = RCs[row].x, gs = Gs[row];
        float rt = RCt[row].x, gt = Gt[row];
        ru_s[r] = rs; vu_s[r] = -rs * gs;
        ru_t[r] = rt; vu_t[r] = -rt * gt;
    }

    float acc0 = 0.0f, acc1 = 0.0f;
#pragma unroll 2
    for (int jj = 0; jj < JC; jj++) {
        const int j = j0 + jj;
        const float gjs = Gs[j * NPTS + k];   // coalesced, L2-resident
        const float gjt = Gt[j * NPTS + k];
#pragma unroll
        for (int r = 0; r < TI; r++) {
            const int row = (i0 + r) * NPTS + j;      // wave-uniform address
            const float2 pcs = RCs[row];              // -> s_load_dwordx2
            const float2 pct = RCt[row];
            float ws = fmaf(ru_s[r], gjs + pcs.y, vu_s[r]);
            float wt = fmaf(ru_t[r], gjt + pct.y, vu_t[r]);
            float mt = pct.x * wt;
            float d  = fmaf(pcs.x, ws, -mt);
            float q  = d * d;
            float u  = fmaf(2.0f, fabsf(d), -1.0f);
            float m  = __builtin_amdgcn_fmed3f(q, u, 1.0f);
            if (r & 1) acc1 = fmaf(0.5f, m, acc1);
            else       acc0 = fmaf(0.5f, m, acc0);
        }
    }

    float acc = acc0 + acc1;
#pragma unroll
    for (int off = 32; off > 0; off >>= 1)
        acc += __shfl_down(acc, off, 64);

    __shared__ float wsum[NPTS / 64];
    const int wid  = k >> 6;
    const int lane = k & 63;
    if (lane == 0) wsum[wid] = acc;
    __syncthreads();
    if (k == 0) {
        float s = 0.0f;
#pragma unroll
        for (int w = 0; w < NPTS / 64; w++) s += wsum[w];
        atomicAdd(out, s * (1.0f / (384.0f * 384.0f * 384.0f)));
    }
}

extern "C" void kernel_launch(void* const* d_in, const int* in_sizes, int n_in,
                              void* d_out, int out_size, void* d_ws, size_t ws_size,
                              hipStream_t stream) {
    const float* student = (const float*)d_in[0];
    const float* teacher = (const float*)d_in[1];
    float* out = (float*)d_out;

    // workspace layout (floats): Gs, Gt [N*N], RCs, RCt [N*N float2], sqn [2*N]
    float*  Gs  = (float*)d_ws;
    float*  Gt  = Gs + NPTS * NPTS;
    float2* RCs = (float2*)(Gt + NPTS * NPTS);
    float2* RCt = RCs + NPTS * NPTS;
    float*  sqn = (float*)(RCt + NPTS * NPTS);

    prep_kernel<<<dim3(NPTS / 4, 2), 256, 0, stream>>>(student, teacher, sqn, out);

    gram_kernel<<<dim3(NPTS / 32, NPTS / 32, 2), dim3(16, 16), 0, stream>>>(
        student, teacher, sqn, Gs, Gt, RCs, RCt);

    rkd_main_kernel<<<dim3(NPTS / TI, NPTS / JC), NPTS, 0, stream>>>(
        Gs, Gt, RCs, RCt, out);
}

// Round 3
// 114.876 us; speedup vs baseline: 1.0267x; 1.0267x over previous
//
#include <hip/hip_runtime.h>
#include <hip/hip_bf16.h>

#define NPTS 384
#define IT 16          // i's per main-kernel block
#define NZI (NPTS/IT)  // 24 i-chunks
#define DIMS 256

// ---------------------------------------------------------------------------
// Kernel 1: fused sqnorm + Gram + derived matrices, per 32x32 tile.
// Outputs for each matrix m in {s,t}:
//   G[i][j]  = e_i . e_j
//   UH[i][j] = { u, h } = { (i==j ? 0 : 1/max(||e_i-e_j||,eps)),  G_ii/2 - G_ij }
// grid (12, 12, 2): z selects matrix. Block 16x16.
// Also zeroes out[0] from block (0,0,0).
// ---------------------------------------------------------------------------
__global__ __launch_bounds__(256) void gram_kernel(
        const float* __restrict__ Es, const float* __restrict__ Et,
        float* __restrict__ Gs, float* __restrict__ Gt,
        float2* __restrict__ UHs, float2* __restrict__ UHt,
        float* __restrict__ out) {
    const int z = blockIdx.z;
    const float* __restrict__ E  = z ? Et : Es;
    float*       __restrict__ G  = z ? Gt : Gs;
    float2*      __restrict__ UH = z ? UHt : UHs;

    const int tx = threadIdx.x;   // 0..15
    const int ty = threadIdx.y;   // 0..15
    const int t  = ty * 16 + tx;  // 0..255
    const int i0 = blockIdx.x * 32;
    const int j0 = blockIdx.y * 32;

    if (blockIdx.x == 0 && blockIdx.y == 0 && z == 0 && t == 0) out[0] = 0.0f;

    // --- row squared-norms for the 32 i-rows and 32 j-rows -> LDS ---
    __shared__ float sn[64];
    {
        const int r = t >> 2;          // 0..63
        const int p = t & 3;           // quarter of the row
        const int row = (r < 32) ? (i0 + r) : (j0 + r - 32);
        const float4* __restrict__ src = (const float4*)(E + row * DIMS) + p * 16;
        float s = 0.f;
#pragma unroll
        for (int k = 0; k < 16; k++) {
            float4 v = src[k];
            s += v.x * v.x + v.y * v.y + v.z * v.z + v.w * v.w;
        }
        s += __shfl_xor(s, 1, 64);
        s += __shfl_xor(s, 2, 64);
        if (p == 0) sn[r] = s;
    }
    __syncthreads();

    // --- Gram 2x2 micro-tile, LDS-free (E is L1-resident) ---
    const int i = i0 + 2 * ty;
    const int j = j0 + 2 * tx;
    const float4* __restrict__ a0 = (const float4*)(E + i * DIMS);
    const float4* __restrict__ a1 = (const float4*)(E + (i + 1) * DIMS);
    const float4* __restrict__ b0 = (const float4*)(E + j * DIMS);
    const float4* __restrict__ b1 = (const float4*)(E + (j + 1) * DIMS);

    float g00 = 0.f, g01 = 0.f, g10 = 0.f, g11 = 0.f;
#pragma unroll 8
    for (int k = 0; k < DIMS / 4; k++) {
        float4 av0 = a0[k], av1 = a1[k], bv0 = b0[k], bv1 = b1[k];
        g00 = fmaf(av0.x, bv0.x, g00); g00 = fmaf(av0.y, bv0.y, g00);
        g00 = fmaf(av0.z, bv0.z, g00); g00 = fmaf(av0.w, bv0.w, g00);
        g01 = fmaf(av0.x, bv1.x, g01); g01 = fmaf(av0.y, bv1.y, g01);
        g01 = fmaf(av0.z, bv1.z, g01); g01 = fmaf(av0.w, bv1.w, g01);
        g10 = fmaf(av1.x, bv0.x, g10); g10 = fmaf(av1.y, bv0.y, g10);
        g10 = fmaf(av1.z, bv0.z, g10); g10 = fmaf(av1.w, bv0.w, g10);
        g11 = fmaf(av1.x, bv1.x, g11); g11 = fmaf(av1.y, bv1.y, g11);
        g11 = fmaf(av1.z, bv1.z, g11); g11 = fmaf(av1.w, bv1.w, g11);
    }

    const float g[2][2] = {{g00, g01}, {g10, g11}};
    const float si[2] = {sn[2 * ty], sn[2 * ty + 1]};
    const float sj[2] = {sn[32 + 2 * tx], sn[32 + 2 * tx + 1]};
#pragma unroll
    for (int r = 0; r < 2; r++) {
#pragma unroll
        for (int c = 0; c < 2; c++) {
            const int ii = i + r, jj = j + c;
            const float gv = g[r][c];
            const float v  = si[r] + sj[c] - 2.0f * gv;
            const float n  = sqrtf(fmaxf(v, 0.0f));
            const float u  = (ii == jj) ? 0.0f : (1.0f / fmaxf(n, 1e-12f));
            G[ii * NPTS + jj]  = gv;
            UH[ii * NPTS + jj] = make_float2(u, 0.5f * si[r] - gv);
        }
    }
}

// ---------------------------------------------------------------------------
// Kernel 2: main reduction over the triangular (jt<=kt) tile set.
//   angle_ijk = u_ij * u_ik * (G_jk + h_ij + h_ik)
//   smooth_l1(d) = 0.5 * med3(d*d, 2|d|-1, 1)
// Block: 64x64 (j,k) tile, 16x16 threads, 4x4 micro-tile, IT i's per block.
// j<->k symmetry: off-diag tiles weight 2, diag tiles per-element {2,1,0}.
// Zero LDS / zero uniform loads in the inner loop.
// ---------------------------------------------------------------------------
__global__ __launch_bounds__(256) void rkd_main_kernel(
        const float* __restrict__ Gs, const float* __restrict__ Gt,
        const float2* __restrict__ UHs, const float2* __restrict__ UHt,
        float* __restrict__ out) {
    // triangular decode: blockIdx.x in [0,21) -> (jt <= kt), both in [0,6)
    const int tlin = blockIdx.x;
    const int kt = (int)((sqrtf(8.0f * (float)tlin + 1.0f) - 1.0f) * 0.5f);
    const int jt = tlin - (kt * (kt + 1)) / 2;

    const int tx = threadIdx.x;    // k-dim, 0..15
    const int ty = threadIdx.y;    // j-dim, 0..15
    const int jb = jt * 64 + 4 * ty;
    const int kb = kt * 64 + 4 * tx;
    const int ibase = blockIdx.y * IT;

    // weights (0.5 * multiplicity), i-independent
    float wh[4][4];
    const bool offd = (jt != kt);
#pragma unroll
    for (int a = 0; a < 4; a++)
#pragma unroll
        for (int b = 0; b < 4; b++) {
            const int jj = jb + a, kk = kb + b;
            const float w2 = offd ? 2.0f : (kk > jj ? 2.0f : (kk == jj ? 1.0f : 0.0f));
            wh[a][b] = 0.5f * w2;
        }

    // G tile -> registers (i-independent)
    float gs[4][4], gt[4][4];
#pragma unroll
    for (int a = 0; a < 4; a++) {
        const float4 vs = *(const float4*)(Gs + (jb + a) * NPTS + kb);
        const float4 vt = *(const float4*)(Gt + (jb + a) * NPTS + kb);
        gs[a][0] = vs.x; gs[a][1] = vs.y; gs[a][2] = vs.z; gs[a][3] = vs.w;
        gt[a][0] = vt.x; gt[a][1] = vt.y; gt[a][2] = vt.z; gt[a][3] = vt.w;
    }

    // UH row pointers (float4 = 2 float2 elems); row stride in float4 = NPTS/2
    const float4* __restrict__ pjs = (const float4*)(UHs + (size_t)ibase * NPTS + jb);
    const float4* __restrict__ pjt = (const float4*)(UHt + (size_t)ibase * NPTS + jb);
    const float4* __restrict__ pks = (const float4*)(UHs + (size_t)ibase * NPTS + kb);
    const float4* __restrict__ pkt = (const float4*)(UHt + (size_t)ibase * NPTS + kb);

    float acc = 0.0f;
#pragma unroll 2
    for (int iz = 0; iz < IT; iz++) {
        const int ro = iz * (NPTS / 2);
        const float4 js0 = pjs[ro], js1 = pjs[ro + 1];
        const float4 jt0 = pjt[ro], jt1 = pjt[ro + 1];
        const float4 ks0 = pks[ro], ks1 = pks[ro + 1];
        const float4 kt0 = pkt[ro], kt1 = pkt[ro + 1];

        const float u_sj[4] = {js0.x, js0.z, js1.x, js1.z};
        const float h_sj[4] = {js0.y, js0.w, js1.y, js1.w};
        const float u_tj[4] = {jt0.x, jt0.z, jt1.x, jt1.z};
        const float h_tj[4] = {jt0.y, jt0.w, jt1.y, jt1.w};
        const float u_sk[4] = {ks0.x, ks0.z, ks1.x, ks1.z};
        const float h_sk[4] = {ks0.y, ks0.w, ks1.y, ks1.w};
        const float u_tk[4] = {kt0.x, kt0.z, kt1.x, kt1.z};
        const float h_tk[4] = {kt0.y, kt0.w, kt1.y, kt1.w};

#pragma unroll
        for (int a = 0; a < 4; a++) {
            const float usa = u_sj[a], hsa = h_sj[a];
            const float uta = u_tj[a], hta = h_tj[a];
#pragma unroll
            for (int b = 0; b < 4; b++) {
                const float ts = gs[a][b] + hsa + h_sk[b];  // v_add3
                const float tt = gt[a][b] + hta + h_tk[b];
                const float ps = usa * u_sk[b];
                const float pt = uta * u_tk[b];
                const float mt = pt * tt;
                const float d  = fmaf(ps, ts, -mt);
                const float q  = d * d;
                const float w  = fmaf(2.0f, fabsf(d), -1.0f);
                const float l  = __builtin_amdgcn_fmed3f(q, w, 1.0f);
                acc = fmaf(wh[a][b], l, acc);
            }
        }
    }

    // reduction: wave -> block -> atomic
#pragma unroll
    for (int off = 32; off > 0; off >>= 1)
        acc += __shfl_down(acc, off, 64);

    __shared__ float wsum[4];
    const int tid  = ty * 16 + tx;
    const int wid  = tid >> 6;
    const int lane = tid & 63;
    if (lane == 0) wsum[wid] = acc;
    __syncthreads();
    if (tid == 0) {
        const float s = wsum[0] + wsum[1] + wsum[2] + wsum[3];
        atomicAdd(out, s * (1.0f / (384.0f * 384.0f * 384.0f)));
    }
}

extern "C" void kernel_launch(void* const* d_in, const int* in_sizes, int n_in,
                              void* d_out, int out_size, void* d_ws, size_t ws_size,
                              hipStream_t stream) {
    const float* student = (const float*)d_in[0];
    const float* teacher = (const float*)d_in[1];
    float* out = (float*)d_out;

    // workspace: Gs, Gt [N*N float], UHs, UHt [N*N float2] (16B-aligned offsets)
    float*  Gs  = (float*)d_ws;
    float*  Gt  = Gs + NPTS * NPTS;
    float2* UHs = (float2*)(Gt + NPTS * NPTS);
    float2* UHt = UHs + NPTS * NPTS;

    gram_kernel<<<dim3(NPTS / 32, NPTS / 32, 2), dim3(16, 16), 0, stream>>>(
        student, teacher, Gs, Gt, UHs, UHt, out);

    rkd_main_kernel<<<dim3(21, NZI), dim3(16, 16), 0, stream>>>(
        Gs, Gt, UHs, UHt, out);
}

// Round 4
// 109.248 us; speedup vs baseline: 1.0796x; 1.0515x over previous
//
#include <hip/hip_runtime.h>
#include <hip/hip_bf16.h>

#define NPTS 384
#define NN (NPTS * NPTS)
#define DIMS 256
#define KSPLIT 4
#define KCH (DIMS / KSPLIT)   // 64 floats per K-chunk
#define IT 8                  // i's per main-kernel block
#define NZI (NPTS / IT)       // 48 i-chunks

// ---------------------------------------------------------------------------
// Kernel 1: K-split Gram partials.
// grid (12, 12, 8): z = matrix*4 + kchunk. Block 16x16, 2x2 micro-tile.
// P[(m*4+kc)][i][j] = sum_{k in chunk} E[i][k]*E[j][k]
// 4608 waves (~4.5/SIMD) so HBM latency is TLP-hidden; short per-thread chains.
// ---------------------------------------------------------------------------
__global__ __launch_bounds__(256, 4) void gram_part_kernel(
        const float* __restrict__ Es, const float* __restrict__ Et,
        float* __restrict__ P) {
    const int m  = blockIdx.z >> 2;
    const int kc = (blockIdx.z & 3) * KCH;
    const float* __restrict__ E = m ? Et : Es;
    float* __restrict__ Gp = P + (size_t)blockIdx.z * NN;

    const int tx = threadIdx.x;   // 0..15
    const int ty = threadIdx.y;   // 0..15
    const int i  = blockIdx.x * 32 + 2 * ty;
    const int j  = blockIdx.y * 32 + 2 * tx;

    const float4* __restrict__ a0 = (const float4*)(E + i * DIMS + kc);
    const float4* __restrict__ a1 = (const float4*)(E + (i + 1) * DIMS + kc);
    const float4* __restrict__ b0 = (const float4*)(E + j * DIMS + kc);
    const float4* __restrict__ b1 = (const float4*)(E + (j + 1) * DIMS + kc);

    float g00 = 0.f, g01 = 0.f, g10 = 0.f, g11 = 0.f;
#pragma unroll
    for (int k = 0; k < KCH / 4; k++) {
        const float4 av0 = a0[k], av1 = a1[k], bv0 = b0[k], bv1 = b1[k];
        g00 = fmaf(av0.x, bv0.x, g00); g00 = fmaf(av0.y, bv0.y, g00);
        g00 = fmaf(av0.z, bv0.z, g00); g00 = fmaf(av0.w, bv0.w, g00);
        g01 = fmaf(av0.x, bv1.x, g01); g01 = fmaf(av0.y, bv1.y, g01);
        g01 = fmaf(av0.z, bv1.z, g01); g01 = fmaf(av0.w, bv1.w, g01);
        g10 = fmaf(av1.x, bv0.x, g10); g10 = fmaf(av1.y, bv0.y, g10);
        g10 = fmaf(av1.z, bv0.z, g10); g10 = fmaf(av1.w, bv0.w, g10);
        g11 = fmaf(av1.x, bv1.x, g11); g11 = fmaf(av1.y, bv1.y, g11);
        g11 = fmaf(av1.z, bv1.z, g11); g11 = fmaf(av1.w, bv1.w, g11);
    }

    *(float2*)(Gp + i * NPTS + j)       = make_float2(g00, g01);
    *(float2*)(Gp + (i + 1) * NPTS + j) = make_float2(g10, g11);
}

// ---------------------------------------------------------------------------
// Kernel 2: sum partials -> G; derive UH = {u, h}:
//   u = (i==j ? 0 : 1/max(sqrt(G_ii - 2G_ij + G_jj), eps)),  h = G_ii/2 - G_ij
// (diagonal of G IS the squared norm — no separate sqnorm pass)
// grid 1152 x 256 threads, one (z,i,j) cell per thread. Also zeroes out[0].
// ---------------------------------------------------------------------------
__global__ __launch_bounds__(256, 4) void derive_kernel(
        const float* __restrict__ P,
        float* __restrict__ Gs, float* __restrict__ Gt,
        float2* __restrict__ UHs, float2* __restrict__ UHt,
        float* __restrict__ out) {
    const int idx = blockIdx.x * 256 + threadIdx.x;   // [0, 2*NN)
    if (idx == 0) out[0] = 0.0f;
    const int z   = idx / NN;
    const int rem = idx - z * NN;
    const int i   = rem / NPTS;
    const int j   = rem - i * NPTS;

    const float* __restrict__ bz = P + (size_t)z * 4 * NN;
    const int di = i * (NPTS + 1);
    const int dj = j * (NPTS + 1);

    const float g   = bz[rem] + bz[NN + rem] + bz[2 * NN + rem] + bz[3 * NN + rem];
    const float gii = bz[di]  + bz[NN + di]  + bz[2 * NN + di]  + bz[3 * NN + di];
    const float gjj = bz[dj]  + bz[NN + dj]  + bz[2 * NN + dj]  + bz[3 * NN + dj];

    const float v = gii + gjj - 2.0f * g;
    const float n = sqrtf(fmaxf(v, 0.0f));
    const float u = (i == j) ? 0.0f : (1.0f / fmaxf(n, 1e-12f));

    (z ? Gt : Gs)[rem]   = g;
    (z ? UHt : UHs)[rem] = make_float2(u, 0.5f * gii - g);
}

// ---------------------------------------------------------------------------
// Kernel 3: main reduction over triangular (jt<=kt) 64x64 tile set.
//   angle_ijk = u_ij * u_ik * (G_jk + h_ij + h_ik)
//   smooth_l1(d) = 0.5 * med3(d*d, 2|d|-1, 1)
// 16x16 threads, 4x4 micro-tile, IT=8 i's per block (1008 blocks ~3.9 w/SIMD).
// Explicit register software-pipeline: prefetch next-i's 8 float4 while
// computing current (compute ~320 cyc covers L2/L3 latency).
// ---------------------------------------------------------------------------
__global__ __launch_bounds__(256, 3) void rkd_main_kernel(
        const float* __restrict__ Gs, const float* __restrict__ Gt,
        const float2* __restrict__ UHs, const float2* __restrict__ UHt,
        float* __restrict__ out) {
    const int tlin = blockIdx.x;
    const int kt = (int)((sqrtf(8.0f * (float)tlin + 1.0f) - 1.0f) * 0.5f);
    const int jt = tlin - (kt * (kt + 1)) / 2;

    const int tx = threadIdx.x;    // k-dim
    const int ty = threadIdx.y;    // j-dim
    const int jb = jt * 64 + 4 * ty;
    const int kb = kt * 64 + 4 * tx;
    const int ibase = blockIdx.y * IT;

    // G tile -> registers (i-independent)
    float gs[4][4], gt[4][4];
#pragma unroll
    for (int a = 0; a < 4; a++) {
        const float4 vs = *(const float4*)(Gs + (jb + a) * NPTS + kb);
        const float4 vt = *(const float4*)(Gt + (jb + a) * NPTS + kb);
        gs[a][0] = vs.x; gs[a][1] = vs.y; gs[a][2] = vs.z; gs[a][3] = vs.w;
        gt[a][0] = vt.x; gt[a][1] = vt.y; gt[a][2] = vt.z; gt[a][3] = vt.w;
    }

    // UH row pointers (float4 = 2 float2); row stride NPTS/2 float4
    const float4* __restrict__ pjs = (const float4*)(UHs + (size_t)ibase * NPTS + jb);
    const float4* __restrict__ pjt = (const float4*)(UHt + (size_t)ibase * NPTS + jb);
    const float4* __restrict__ pks = (const float4*)(UHs + (size_t)ibase * NPTS + kb);
    const float4* __restrict__ pkt = (const float4*)(UHt + (size_t)ibase * NPTS + kb);

    const bool offd = (jt != kt);
    float wh[4][4];
#pragma unroll
    for (int a = 0; a < 4; a++)
#pragma unroll
        for (int b = 0; b < 4; b++) {
            const int jj = jb + a, kk = kb + b;
            wh[a][b] = (kk > jj) ? 1.0f : ((kk == jj) ? 0.5f : 0.0f);
        }

    float4 L[8];
    L[0] = pjs[0]; L[1] = pjs[1];
    L[2] = pjt[0]; L[3] = pjt[1];
    L[4] = pks[0]; L[5] = pks[1];
    L[6] = pkt[0]; L[7] = pkt[1];

    float acc = 0.0f;
#pragma unroll 2
    for (int iz = 0; iz < IT; iz++) {
        // prefetch next i's rows (clamped; redundant last loads are L1-hot)
        const int nz = (iz + 1 < IT) ? iz + 1 : iz;
        const int ro = nz * (NPTS / 2);
        float4 Ln[8];
        Ln[0] = pjs[ro];     Ln[1] = pjs[ro + 1];
        Ln[2] = pjt[ro];     Ln[3] = pjt[ro + 1];
        Ln[4] = pks[ro];     Ln[5] = pks[ro + 1];
        Ln[6] = pkt[ro];     Ln[7] = pkt[ro + 1];

        const float u_sj[4] = {L[0].x, L[0].z, L[1].x, L[1].z};
        const float h_sj[4] = {L[0].y, L[0].w, L[1].y, L[1].w};
        const float u_tj[4] = {L[2].x, L[2].z, L[3].x, L[3].z};
        const float h_tj[4] = {L[2].y, L[2].w, L[3].y, L[3].w};
        const float u_sk[4] = {L[4].x, L[4].z, L[5].x, L[5].z};
        const float h_sk[4] = {L[4].y, L[4].w, L[5].y, L[5].w};
        const float u_tk[4] = {L[6].x, L[6].z, L[7].x, L[7].z};
        const float h_tk[4] = {L[6].y, L[6].w, L[7].y, L[7].w};

        if (offd) {
#pragma unroll
            for (int a = 0; a < 4; a++) {
                const float usa = u_sj[a], hsa = h_sj[a];
                const float uta = u_tj[a], hta = h_tj[a];
#pragma unroll
                for (int b = 0; b < 4; b++) {
                    const float ts = gs[a][b] + hsa + h_sk[b];
                    const float tt = gt[a][b] + hta + h_tk[b];
                    const float ps = usa * u_sk[b];
                    const float pt = uta * u_tk[b];
                    const float mt = pt * tt;
                    const float d  = fmaf(ps, ts, -mt);
                    const float q  = d * d;
                    const float w  = fmaf(2.0f, fabsf(d), -1.0f);
                    acc += __builtin_amdgcn_fmed3f(q, w, 1.0f);  // weight 2*0.5=1
                }
            }
        } else {
#pragma unroll
            for (int a = 0; a < 4; a++) {
                const float usa = u_sj[a], hsa = h_sj[a];
                const float uta = u_tj[a], hta = h_tj[a];
#pragma unroll
                for (int b = 0; b < 4; b++) {
                    const float ts = gs[a][b] + hsa + h_sk[b];
                    const float tt = gt[a][b] + hta + h_tk[b];
                    const float ps = usa * u_sk[b];
                    const float pt = uta * u_tk[b];
                    const float mt = pt * tt;
                    const float d  = fmaf(ps, ts, -mt);
                    const float q  = d * d;
                    const float w  = fmaf(2.0f, fabsf(d), -1.0f);
                    const float l  = __builtin_amdgcn_fmed3f(q, w, 1.0f);
                    acc = fmaf(wh[a][b], l, acc);
                }
            }
        }

#pragma unroll
        for (int r = 0; r < 8; r++) L[r] = Ln[r];
    }

    // reduction: wave -> block -> atomic
#pragma unroll
    for (int off = 32; off > 0; off >>= 1)
        acc += __shfl_down(acc, off, 64);

    __shared__ float wsum[4];
    const int tid  = ty * 16 + tx;
    const int wid  = tid >> 6;
    const int lane = tid & 63;
    if (lane == 0) wsum[wid] = acc;
    __syncthreads();
    if (tid == 0) {
        const float s = wsum[0] + wsum[1] + wsum[2] + wsum[3];
        atomicAdd(out, s * (1.0f / (384.0f * 384.0f * 384.0f)));
    }
}

extern "C" void kernel_launch(void* const* d_in, const int* in_sizes, int n_in,
                              void* d_out, int out_size, void* d_ws, size_t ws_size,
                              hipStream_t stream) {
    const float* student = (const float*)d_in[0];
    const float* teacher = (const float*)d_in[1];
    float* out = (float*)d_out;

    // ws layout (floats): P[8*NN], Gs[NN], Gt[NN], UHs[2*NN], UHt[2*NN]
    float*  P   = (float*)d_ws;
    float*  Gs  = P + 8 * NN;
    float*  Gt  = Gs + NN;
    float2* UHs = (float2*)(Gt + NN);
    float2* UHt = UHs + NN;

    gram_part_kernel<<<dim3(NPTS / 32, NPTS / 32, 8), dim3(16, 16), 0, stream>>>(
        student, teacher, P);

    derive_kernel<<<dim3(2 * NN / 256), 256, 0, stream>>>(
        P, Gs, Gt, UHs, UHt, out);

    rkd_main_kernel<<<dim3(21, NZI), dim3(16, 16), 0, stream>>>(
        Gs, Gt, UHs, UHt, out);
}